// Round 17
// baseline (335.442 us; speedup 1.0000x reference)
//
#include <hip/hip_runtime.h>
#include <hip/hip_bf16.h>

#define Nn 100000
#define Ee 1600000
#define Kk 80000
#define NB ((Nn + 255) / 256)
#define NBK 391              // buckets of 256 dsts: bucket = d >> 8
#define CHK 2048             // edges per binScat block -> 782 blocks
#define G2B 2048             // gather2 grid

typedef unsigned int uint;
typedef unsigned short ushort;

struct Scal {
    uint prefix, remaining;
    float c1[4];
    float c2;
};

__device__ __forceinline__ uint f2ord(float f) {
    uint b = __float_as_uint(f);
    return (b & 0x80000000u) ? ~b : (b | 0x80000000u);
}
__device__ __forceinline__ float lrelu(float v) { return v > 0.f ? v : 0.2f * v; }
__device__ __forceinline__ float2 bf2f2(uint u) {
    return make_float2(__uint_as_float(u << 16), __uint_as_float(u & 0xFFFF0000u));
}
__device__ __forceinline__ uint f2bf2(float a, float b) {
    __hip_bfloat162 h;
    h.x = __float2bfloat16(a);
    h.y = __float2bfloat16(b);
    return *(uint*)&h;
}

// ---------------- init (+ folded constK) ----------------
__global__ __launch_bounds__(256) void initK(uint* bcnt, uint* hist, Scal* sc,
                                             const float* We1, const float* ae1,
                                             const float* We2, const float* ae2) {
    int i = blockIdx.x * 256 + threadIdx.x;
    if (i < NBK) bcnt[i] = 0u;
    if (i < 256) hist[i] = 0u;
    if (i == 0) {
        sc->prefix = 0u; sc->remaining = Kk;
        for (int h = 0; h < 4; h++) {
            float s = 0.f;
            for (int d = 0; d < 4; d++) s += We1[h * 4 + d] * ae1[h * 4 + d];
            sc->c1[h] = s;
        }
        float s2 = 0.f;
        for (int d = 0; d < 128; d++) s2 += We2[d] * ae2[d];
        sc->c2 = s2;
    }
}

// ---------------- layer 1: node GEMM + attn coefficients (bf16 hpre) ----------------
__global__ __launch_bounds__(256) void nodeL1(const float* __restrict__ x,
                                              const float* __restrict__ W1,
                                              const float* __restrict__ as1,
                                              const float* __restrict__ ad1,
                                              uint* __restrict__ hpreB,
                                              float* __restrict__ alS1,
                                              float* __restrict__ alD1) {
    __shared__ float Ws[128 * 16];
    __shared__ float s_as[16], s_ad[16];
    for (int i = threadIdx.x; i < 2048; i += 256) Ws[i] = W1[i];
    if (threadIdx.x < 16) { s_as[threadIdx.x] = as1[threadIdx.x]; s_ad[threadIdx.x] = ad1[threadIdx.x]; }
    __syncthreads();
    int n = blockIdx.x * 256 + threadIdx.x;
    if (n >= Nn) return;
    float acc[16];
#pragma unroll
    for (int j = 0; j < 16; j++) acc[j] = 0.f;
    const float4* xr = (const float4*)(x + (size_t)n * 128);
    for (int t4 = 0; t4 < 32; t4++) {
        float4 xv = xr[t4];
#pragma unroll
        for (int j = 0; j < 16; j++) {
            acc[j] += xv.x * Ws[(t4 * 4 + 0) * 16 + j];
            acc[j] += xv.y * Ws[(t4 * 4 + 1) * 16 + j];
            acc[j] += xv.z * Ws[(t4 * 4 + 2) * 16 + j];
            acc[j] += xv.w * Ws[(t4 * 4 + 3) * 16 + j];
        }
    }
    uint h8[8];
#pragma unroll
    for (int j = 0; j < 8; j++) h8[j] = f2bf2(acc[2 * j], acc[2 * j + 1]);
    uint4* hp = (uint4*)(hpreB + (size_t)n * 8);
    hp[0] = make_uint4(h8[0], h8[1], h8[2], h8[3]);
    hp[1] = make_uint4(h8[4], h8[5], h8[6], h8[7]);
#pragma unroll
    for (int h = 0; h < 4; h++) {
        float s = 0.f, d = 0.f;
#pragma unroll
        for (int q = 0; q < 4; q++) {
            s += acc[h * 4 + q] * s_as[h * 4 + q];
            d += acc[h * 4 + q] * s_ad[h * 4 + q];
        }
        alS1[n * 4 + h] = s;
        alD1[n * 4 + h] = d;
    }
}

// ---------------- CSR build: bucket sort, no per-edge global atomics ----------------
__global__ __launch_bounds__(256) void bucketCnt(const int* __restrict__ ei, uint* __restrict__ bcnt) {
    __shared__ uint h[NBK];
    for (int k = threadIdx.x; k < NBK; k += 256) h[k] = 0u;
    __syncthreads();
    for (int e = blockIdx.x * 256 + threadIdx.x; e < Ee; e += gridDim.x * 256)
        atomicAdd(&h[((uint)ei[Ee + e]) >> 8], 1u);
    __syncthreads();
    for (int k = threadIdx.x; k < NBK; k += 256)
        if (h[k]) atomicAdd(&bcnt[k], h[k]);
}

__global__ __launch_bounds__(512) void scanBk(const uint* __restrict__ bcnt, uint* __restrict__ boff,
                                              uint* __restrict__ gcur) {
    __shared__ uint s[512];
    int t = threadIdx.x;
    uint v = (t < NBK) ? bcnt[t] : 0u;
    s[t] = v;
    __syncthreads();
    for (int off = 1; off < 512; off <<= 1) {
        uint u = (t >= off) ? s[t - off] : 0u;
        __syncthreads();
        s[t] += u;
        __syncthreads();
    }
    if (t < NBK) { boff[t] = s[t] - v; gcur[t] = 0u; }
    if (t == 0) boff[NBK] = Ee;
}

__global__ __launch_bounds__(256) void binScat(const int* __restrict__ ei, const float* __restrict__ ea,
                                               const uint* __restrict__ boff, uint* __restrict__ gcur,
                                               uint2* __restrict__ bsE, ushort* __restrict__ bsD) {
    __shared__ uint h[NBK], base[NBK], h2[NBK];
    int t = threadIdx.x;
    for (int k = t; k < NBK; k += 256) h[k] = 0u;
    __syncthreads();
    int estart = blockIdx.x * CHK;
    int eend = min(Ee, estart + CHK);
    for (int e = estart + t; e < eend; e += 256)
        atomicAdd(&h[((uint)ei[Ee + e]) >> 8], 1u);
    __syncthreads();
    for (int k = t; k < NBK; k += 256) {
        base[k] = h[k] ? atomicAdd(&gcur[k], h[k]) : 0u;
        h2[k] = 0u;
    }
    __syncthreads();
    for (int e = estart + t; e < eend; e += 256) {
        uint d = (uint)ei[Ee + e];
        uint b = d >> 8;
        uint r = atomicAdd(&h2[b], 1u);
        uint pos = boff[b] + base[b] + r;
        bsE[pos] = make_uint2((uint)ei[e], __float_as_uint(ea[e]));
        bsD[pos] = (ushort)(d & 255u);
    }
}

// rank + scan + place fused: 1 block per 256-dst bucket. Writes rowstart AND csr_p8.
__global__ __launch_bounds__(256) void rankPlace(const uint* __restrict__ boff, const uint2* __restrict__ bsE,
                                                 const ushort* __restrict__ bsD,
                                                 uint2* __restrict__ csr_p8, uint* __restrict__ rowstart) {
    __shared__ uint ldeg[256];
    __shared__ uint lscan[256];
    __shared__ uint s[256];
    int b = blockIdx.x, t = threadIdx.x;
    ldeg[t] = 0u;
    __syncthreads();
    uint r0 = boff[b], r1 = boff[b + 1];
    for (uint i = r0 + t; i < r1; i += 256)
        atomicAdd(&ldeg[bsD[i]], 1u);
    __syncthreads();
    uint v = ldeg[t];
    s[t] = v;
    __syncthreads();
    for (int off = 1; off < 256; off <<= 1) {
        uint u = (t >= off) ? s[t - off] : 0u;
        __syncthreads();
        s[t] += u;
        __syncthreads();
    }
    lscan[t] = s[t] - v;   // exclusive
    __syncthreads();
    uint bb = boff[b];
    int nd = b * 256 + t;
    if (nd < Nn) rowstart[nd] = bb + lscan[t];
    if (b == 0 && t == 0) rowstart[Nn] = Ee;
    ldeg[t] = 0u;          // reuse as cursor
    __syncthreads();
    for (uint i = r0 + t; i < r1; i += 256) {
        ushort dl = bsD[i];
        uint r = atomicAdd(&ldeg[dl], 1u);
        csr_p8[bb + lscan[dl] + r] = bsE[i];
    }
}

// ---------------- layer-1 gather: fused partial, thread per (dst,head), bf16 hpre ----------------
__global__ __launch_bounds__(256) void gather1f(const uint2* __restrict__ csr_p8,
                                                const uint* __restrict__ rowstart,
                                                const float* __restrict__ alS1, const float* __restrict__ alD1,
                                                const uint* __restrict__ hpreB, const Scal* __restrict__ scc,
                                                const float* __restrict__ b1, const float* __restrict__ Wrel,
                                                const float* __restrict__ Wroot,
                                                float* __restrict__ h1, float* __restrict__ p,
                                                float* __restrict__ q) {
    int tid = blockIdx.x * 256 + threadIdx.x;
    if (tid >= Nn * 4) return;
    int d = tid >> 2, h = tid & 3;
    uint r0 = rowstart[d], r1 = rowstart[d + 1];
    float ad = alD1[tid];
    float c1h = scc->c1[h];
    float den = 0.f;
    float4 acc = {0.f, 0.f, 0.f, 0.f};
#pragma unroll 8
    for (uint i = r0; i < r1; i++) {
        uint2 p8 = csr_p8[i];
        int s = (int)p8.x;
        float e = __expf(lrelu(alS1[s * 4 + h] + __uint_as_float(p8.y) * c1h + ad));
        uint2 hb = *(const uint2*)(hpreB + (size_t)s * 8 + h * 2);
        float2 f0 = bf2f2(hb.x), f1 = bf2f2(hb.y);
        den += e;
        acc.x += e * f0.x; acc.y += e * f0.y;
        acc.z += e * f1.x; acc.w += e * f1.y;
    }
    float inv = 1.f / fmaxf(den, 1e-16f);
    float4 o;
    o.x = fmaxf(acc.x * inv + b1[h * 4 + 0], 0.f);
    o.y = fmaxf(acc.y * inv + b1[h * 4 + 1], 0.f);
    o.z = fmaxf(acc.z * inv + b1[h * 4 + 2], 0.f);
    o.w = fmaxf(acc.w * inv + b1[h * 4 + 3], 0.f);
    *(float4*)(h1 + (size_t)d * 16 + h * 4) = o;
    float pp = o.x * Wrel[h * 4 + 0] + o.y * Wrel[h * 4 + 1] + o.z * Wrel[h * 4 + 2] + o.w * Wrel[h * 4 + 3];
    float qq = o.x * Wroot[h * 4 + 0] + o.y * Wroot[h * 4 + 1] + o.z * Wroot[h * 4 + 2] + o.w * Wroot[h * 4 + 3];
    pp += __shfl_xor(pp, 1); pp += __shfl_xor(pp, 2);
    qq += __shfl_xor(qq, 1); qq += __shfl_xor(qq, 2);
    if (h == 0) { p[d] = pp; q[d] = qq; }
}

// ---------------- SAGPool score + first radix histogram (shift=24) fused ----------------
__global__ __launch_bounds__(256) void scoreH(const uint2* __restrict__ csr_p8, const uint* __restrict__ rowstart,
                                              const float* __restrict__ p, const float* __restrict__ q,
                                              const float* __restrict__ brel,
                                              float* __restrict__ score, uint* __restrict__ dkey,
                                              uint* __restrict__ hist) {
    __shared__ uint lh[256];
    lh[threadIdx.x] = 0u;
    __syncthreads();
    int d = blockIdx.x * 256 + threadIdx.x;
    if (d < Nn) {
        uint r0 = rowstart[d], r1 = rowstart[d + 1];
        float s = brel[0] + q[d];
#pragma unroll 8
        for (uint i = r0; i < r1; i++) s += p[(int)csr_p8[i].x];
        score[d] = s;
        uint k = ~f2ord(s);
        dkey[d] = k;
        atomicAdd(&lh[k >> 24], 1u);
    }
    __syncthreads();
    if (lh[threadIdx.x]) atomicAdd(&hist[threadIdx.x], lh[threadIdx.x]);
}

// ---------------- radix select (multi-block) ----------------
__global__ __launch_bounds__(256) void histK(const uint* __restrict__ dkey, const Scal* __restrict__ sc,
                                             uint* __restrict__ hist, int shift) {
    __shared__ uint lh[256];
    lh[threadIdx.x] = 0u;
    __syncthreads();
    int i = blockIdx.x * 256 + threadIdx.x;
    if (i < Nn) {
        uint d = dkey[i];
        if ((d >> (shift + 8)) == sc->prefix) atomicAdd(&lh[(d >> shift) & 255u], 1u);
    }
    __syncthreads();
    if (lh[threadIdx.x]) atomicAdd(&hist[threadIdx.x], lh[threadIdx.x]);
}

__global__ __launch_bounds__(256) void selP(Scal* sc, uint* hist) {
    __shared__ uint s[256];
    int t = threadIdx.x;
    uint c = hist[t];
    s[t] = c;
    __syncthreads();
    for (int off = 1; off < 256; off <<= 1) {
        uint v = (t >= off) ? s[t - off] : 0u;
        __syncthreads();
        s[t] += v;
        __syncthreads();
    }
    uint rem = sc->remaining;
    uint cum = s[t];
    uint cumex = cum - c;
    if (cum >= rem && cumex < rem) {
        sc->remaining = rem - cumex;
        sc->prefix = (sc->prefix << 8) | (uint)t;
    }
    hist[t] = 0u;
}

// eq-count per block (needEq == sc->remaining after last selP)
__global__ __launch_bounds__(256) void eqCnt(const uint* __restrict__ dkey, const Scal* __restrict__ sc,
                                             uint* __restrict__ blkEq) {
    int i = blockIdx.x * 256 + threadIdx.x;
    uint ut = sc->prefix;
    bool eq = (i < Nn) && (dkey[i] == ut);
    __shared__ uint se[4];
    unsigned long long be = __ballot(eq);
    int lane = threadIdx.x & 63, w = threadIdx.x >> 6;
    if (lane == 0) se[w] = (uint)__popcll(be);
    __syncthreads();
    if (threadIdx.x == 0) blkEq[blockIdx.x] = se[0] + se[1] + se[2] + se[3];
}

__global__ __launch_bounds__(512) void prefE(const uint* __restrict__ blkEq, uint* __restrict__ eqPref) {
    __shared__ uint se[512];
    int t = threadIdx.x;
    uint e = (t < NB) ? blkEq[t] : 0u;
    se[t] = e;
    __syncthreads();
    for (int off = 1; off < 512; off <<= 1) {
        uint v1 = (t >= off) ? se[t - off] : 0u;
        __syncthreads();
        se[t] += v1;
        __syncthreads();
    }
    if (t < NB) eqPref[t] = se[t] - e;
}

__global__ __launch_bounds__(256) void keptK(const uint* __restrict__ dkey, const Scal* __restrict__ sc,
                                             const uint* __restrict__ eqPref, int* __restrict__ kept) {
    int i = blockIdx.x * 256 + threadIdx.x;
    uint ut = sc->prefix, needEq = sc->remaining;
    bool inr = i < Nn;
    uint d = inr ? dkey[i] : 0xFFFFFFFFu;
    bool isLt = inr && (d < ut);
    bool isEq = inr && (d == ut);
    __shared__ uint wcnt[4];
    unsigned long long mask = __ballot(isEq);
    int lane = threadIdx.x & 63, w = threadIdx.x >> 6;
    uint lanePre = (uint)__popcll(mask & ((1ull << lane) - 1ull));
    if (lane == 0) wcnt[w] = (uint)__popcll(mask);
    __syncthreads();
    uint wo = 0;
    for (int qq = 0; qq < 4; qq++) if (qq < w) wo += wcnt[qq];
    uint rank = eqPref[blockIdx.x] + wo + lanePre;
    if (inr) kept[i] = (isLt || (isEq && rank < needEq)) ? 1 : 0;
}

// ---------------- layer 2 node transform: bf16 rows; alS2k = kept ? alS2 : -1e30 ----------------
__global__ __launch_bounds__(256) void nodeL2(const float* __restrict__ h1, const float* __restrict__ score,
                                              const int* __restrict__ kept, const float* __restrict__ W2,
                                              const float* __restrict__ as2, const float* __restrict__ ad2,
                                              __hip_bfloat162* __restrict__ h2b, float* __restrict__ alS2k,
                                              float* __restrict__ alD2) {
    __shared__ float Ws[16 * 128];
    for (int i = threadIdx.x; i < 2048; i += 256) Ws[i] = W2[i];
    __syncthreads();
    int wid = (blockIdx.x * 256 + threadIdx.x) >> 6;
    int lane = threadIdx.x & 63;
    if (wid >= Nn) return;
    int n = wid;
    if (!kept[n]) { if (lane == 0) alS2k[n] = -1e30f; return; }
    float t = tanhf(score[n]);
    float x2[16];
    const float* hr = h1 + (size_t)n * 16;
#pragma unroll
    for (int j = 0; j < 16; j++) x2[j] = hr[j] * t;
    int d0 = 2 * lane, d1 = 2 * lane + 1;
    float a0 = 0.f, a1 = 0.f;
    const float2* Wv = (const float2*)Ws;
#pragma unroll
    for (int j = 0; j < 16; j++) {
        float2 wv = Wv[j * 64 + lane];
        a0 += x2[j] * wv.x;
        a1 += x2[j] * wv.y;
    }
    __hip_bfloat162 hb;
    hb.x = __float2bfloat16(a0);
    hb.y = __float2bfloat16(a1);
    h2b[(size_t)n * 64 + lane] = hb;
    float s = a0 * as2[d0] + a1 * as2[d1];
    float dd = a0 * ad2[d0] + a1 * ad2[d1];
#pragma unroll
    for (int off = 32; off; off >>= 1) { s += __shfl_xor(s, off); dd += __shfl_xor(dd, off); }
    if (lane == 0) { alS2k[n] = s; alD2[n] = dd; }
}

// ---------------- layer-2 gather + fused pooling partials ----------------
__global__ __launch_bounds__(256) void gather2g(const uint2* __restrict__ csr_p8,
                                                const uint* __restrict__ rowstart,
                                                const float* __restrict__ alS2k, const float* __restrict__ alD2,
                                                const Scal* __restrict__ scc,
                                                const __hip_bfloat162* __restrict__ h2b, const float* __restrict__ b2,
                                                const float* __restrict__ Wg, const float* __restrict__ bg,
                                                float* __restrict__ pacc, float* __restrict__ pmx,
                                                float* __restrict__ pden) {
    __shared__ float sAtt[4][16][8];
    __shared__ float sMx[4][16][8];
    __shared__ float sDen[4];
    int w = threadIdx.x >> 6, lane = threadIdx.x & 63;
    int g = lane >> 4, t = lane & 15;
    float4 b2a = ((const float4*)b2)[t * 2], b2b = ((const float4*)b2)[t * 2 + 1];
    float4 wga = ((const float4*)Wg)[t * 2], wgb = ((const float4*)Wg)[t * 2 + 1];
    float bg0 = bg[0];
    float c2 = scc->c2;
    const uint* h2u = (const uint*)h2b;
    float att[8], mx8[8], denP = 0.f;
#pragma unroll
    for (int j = 0; j < 8; j++) { att[j] = 0.f; mx8[j] = 0.f; }
    for (int n = blockIdx.x * 4 + w; n < Nn; n += G2B * 4) {
        float sk = alS2k[n];
        if (sk <= -1e29f) continue;   // not kept (sentinel)
        float ad = alD2[n];
        uint r0 = rowstart[n];
        uint len = rowstart[n + 1] - r0;
        float den = 0.f;
        float acc[8];
#pragma unroll
        for (int d = 0; d < 8; d++) acc[d] = 0.f;
#pragma unroll 4
        for (uint base = 0; base < len; base += 4) {
            uint off = base + (uint)g;
            bool act = off < len;
            uint sidx = act ? (r0 + off) : (r0 + len - 1);
            uint2 p8 = csr_p8[sidx];
            int s = (int)p8.x;
            float pv = alS2k[s] + __uint_as_float(p8.y) * c2;
            pv = act ? pv : -1e30f;
            float c = __expf(lrelu(pv + ad));
            uint4 hv = *(const uint4*)(h2u + (size_t)s * 64 + t * 4);
            den += c;
            float2 f;
            f = bf2f2(hv.x); acc[0] += c * f.x; acc[1] += c * f.y;
            f = bf2f2(hv.y); acc[2] += c * f.x; acc[3] += c * f.y;
            f = bf2f2(hv.z); acc[4] += c * f.x; acc[5] += c * f.y;
            f = bf2f2(hv.w); acc[6] += c * f.x; acc[7] += c * f.y;
        }
#pragma unroll
        for (int d = 0; d < 8; d++) {
            acc[d] += __shfl_xor(acc[d], 16);
            acc[d] += __shfl_xor(acc[d], 32);
        }
        den += __shfl_xor(den, 16);
        den += __shfl_xor(den, 32);
        float inv = 1.f / fmaxf(den, 1e-16f);
        float o[8];
        o[0] = fmaxf(acc[0] * inv + b2a.x, 0.f);
        o[1] = fmaxf(acc[1] * inv + b2a.y, 0.f);
        o[2] = fmaxf(acc[2] * inv + b2a.z, 0.f);
        o[3] = fmaxf(acc[3] * inv + b2a.w, 0.f);
        o[4] = fmaxf(acc[4] * inv + b2b.x, 0.f);
        o[5] = fmaxf(acc[5] * inv + b2b.y, 0.f);
        o[6] = fmaxf(acc[6] * inv + b2b.z, 0.f);
        o[7] = fmaxf(acc[7] * inv + b2b.w, 0.f);
        float gp = o[0] * wga.x + o[1] * wga.y + o[2] * wga.z + o[3] * wga.w +
                   o[4] * wgb.x + o[5] * wgb.y + o[6] * wgb.z + o[7] * wgb.w;
#pragma unroll
        for (int off = 8; off; off >>= 1) gp += __shfl_xor(gp, off);
        float e = __expf(gp + bg0);
        denP += e;
#pragma unroll
        for (int j = 0; j < 8; j++) {
            att[j] += e * o[j];
            mx8[j] = fmaxf(mx8[j], o[j]);
        }
    }
    if (g == 0) {
#pragma unroll
        for (int j = 0; j < 8; j++) { sAtt[w][t][j] = att[j]; sMx[w][t][j] = mx8[j]; }
    }
    if (lane == 0) sDen[w] = denP;
    __syncthreads();
    int tid = threadIdx.x;
    if (tid < 128) {
        int tt = tid >> 3, j = tid & 7;
        float a = sAtt[0][tt][j] + sAtt[1][tt][j] + sAtt[2][tt][j] + sAtt[3][tt][j];
        float m = fmaxf(fmaxf(sMx[0][tt][j], sMx[1][tt][j]), fmaxf(sMx[2][tt][j], sMx[3][tt][j]));
        pacc[(size_t)blockIdx.x * 128 + tid] = a;
        pmx[(size_t)blockIdx.x * 128 + tid] = m;
    }
    if (tid == 0) pden[blockIdx.x] = sDen[0] + sDen[1] + sDen[2] + sDen[3];
}

// ---------------- final reduction + output (fused): 128 blocks, one per dim ----------------
__global__ __launch_bounds__(256) void gateOut(const float* __restrict__ pacc, const float* __restrict__ pmx,
                                               const float* __restrict__ pden, float* __restrict__ out) {
    __shared__ float r[256];
    __shared__ float rd[256];
    int b = blockIdx.x, tid = threadIdx.x;
    float a = 0.f, m = 0.f, dsum = 0.f;
    for (int i = tid; i < G2B; i += 256) {
        a += pacc[(size_t)i * 128 + b];
        m = fmaxf(m, pmx[(size_t)i * 128 + b]);
        dsum += pden[i];
    }
    r[tid] = a; rd[tid] = dsum;
    __syncthreads();
    for (int off = 128; off; off >>= 1) {
        if (tid < off) { r[tid] += r[tid + off]; rd[tid] += rd[tid + off]; }
        __syncthreads();
    }
    float asum = r[0], deng = rd[0];
    __syncthreads();
    r[tid] = m;
    __syncthreads();
    for (int off = 128; off; off >>= 1) {
        if (tid < off) r[tid] = fmaxf(r[tid], r[tid + off]);
        __syncthreads();
    }
    if (tid == 0) {
        out[b] = asum / deng;
        out[128 + b] = r[0];
    }
}

extern "C" void kernel_launch(void* const* d_in, const int* in_sizes, int n_in,
                              void* d_out, int out_size, void* d_ws, size_t ws_size,
                              hipStream_t stream) {
    const float* x = (const float*)d_in[0];
    const int* ei = (const int*)d_in[1];
    const float* ea = (const float*)d_in[2];
    const float* W1 = (const float*)d_in[3];
    const float* as1 = (const float*)d_in[4];
    const float* ad1 = (const float*)d_in[5];
    const float* We1 = (const float*)d_in[6];
    const float* ae1 = (const float*)d_in[7];
    const float* b1 = (const float*)d_in[8];
    const float* Wrel = (const float*)d_in[9];
    const float* brel = (const float*)d_in[10];
    const float* Wroot = (const float*)d_in[11];
    const float* W2 = (const float*)d_in[12];
    const float* as2 = (const float*)d_in[13];
    const float* ad2 = (const float*)d_in[14];
    const float* We2 = (const float*)d_in[15];
    const float* ae2 = (const float*)d_in[16];
    const float* b2 = (const float*)d_in[17];
    const float* Wg = (const float*)d_in[18];
    const float* bg = (const float*)d_in[19];
    float* out = (float*)d_out;

    float* base = (float*)d_ws;
    size_t o = 0;
    auto alloc = [&](size_t nf) { float* p2 = base + o; o += nf; return p2; };
    uint2* bsE = (uint2*)alloc((size_t)Ee * 2);
    ushort* bsD = (ushort*)alloc((size_t)Ee / 2);
    uint2* csr_p8 = (uint2*)alloc((size_t)Ee * 2);
    __hip_bfloat162* h2b = (__hip_bfloat162*)alloc((size_t)Nn * 64);
    uint* hpreB = (uint*)alloc((size_t)Nn * 8);   // bf16 [N][16]
    float* h1 = alloc((size_t)Nn * 16);
    float* pacc = alloc((size_t)G2B * 128);
    float* pmx = alloc((size_t)G2B * 128);
    float* pden = alloc(G2B);
    float* alS1 = alloc((size_t)Nn * 4);
    float* alD1 = alloc((size_t)Nn * 4);
    float* p = alloc(Nn);
    float* q = alloc(Nn);
    float* score = alloc(Nn);
    uint* dkey = (uint*)alloc(Nn);
    int* kept = (int*)alloc(Nn);
    float* alS2k = alloc(Nn);
    float* alD2 = alloc(Nn);
    uint* rowstart = (uint*)alloc(Nn + 1);
    uint* hist = (uint*)alloc(256);
    uint* blkEq = (uint*)alloc(NB);
    uint* eqPref = (uint*)alloc(NB);
    uint* bcnt = (uint*)alloc(NBK);
    uint* boff = (uint*)alloc(NBK + 1);
    uint* gcur = (uint*)alloc(NBK);
    Scal* sc = (Scal*)alloc(64);

    auto cdiv = [](long a, long b) { return (int)((a + b - 1) / b); };

    initK<<<NB, 256, 0, stream>>>(bcnt, hist, sc, We1, ae1, We2, ae2);
    nodeL1<<<NB, 256, 0, stream>>>(x, W1, as1, ad1, hpreB, alS1, alD1);
    bucketCnt<<<512, 256, 0, stream>>>(ei, bcnt);
    scanBk<<<1, 512, 0, stream>>>(bcnt, boff, gcur);
    binScat<<<cdiv(Ee, CHK), 256, 0, stream>>>(ei, ea, boff, gcur, bsE, bsD);
    rankPlace<<<NBK, 256, 0, stream>>>(boff, bsE, bsD, csr_p8, rowstart);
    gather1f<<<cdiv((long)Nn * 4, 256), 256, 0, stream>>>(csr_p8, rowstart, alS1, alD1, hpreB, sc,
                                                          b1, Wrel, Wroot, h1, p, q);
    scoreH<<<NB, 256, 0, stream>>>(csr_p8, rowstart, p, q, brel, score, dkey, hist);
    selP<<<1, 256, 0, stream>>>(sc, hist);
    for (int shift = 16; shift >= 0; shift -= 8) {
        histK<<<NB, 256, 0, stream>>>(dkey, sc, hist, shift);
        selP<<<1, 256, 0, stream>>>(sc, hist);
    }
    eqCnt<<<NB, 256, 0, stream>>>(dkey, sc, blkEq);
    prefE<<<1, 512, 0, stream>>>(blkEq, eqPref);
    keptK<<<NB, 256, 0, stream>>>(dkey, sc, eqPref, kept);
    nodeL2<<<cdiv(Nn, 4), 256, 0, stream>>>(h1, score, kept, W2, as2, ad2, h2b, alS2k, alD2);
    gather2g<<<G2B, 256, 0, stream>>>(csr_p8, rowstart, alS2k, alD2, sc,
                                      h2b, b2, Wg, bg, pacc, pmx, pden);
    gateOut<<<128, 256, 0, stream>>>(pacc, pmx, pden, out);
}

// Round 18
// 323.661 us; speedup vs baseline: 1.0364x; 1.0364x over previous
//
#include <hip/hip_runtime.h>
#include <hip/hip_bf16.h>

#define Nn 100000
#define Ee 1600000
#define Kk 80000
#define NB ((Nn + 255) / 256)
#define NBK 196              // buckets of 512 dsts: bucket = d >> 9
#define CHK 8192             // edges per binScat block -> 196 blocks
#define G2B 2048             // gather2 grid

typedef unsigned int uint;
typedef unsigned short ushort;

struct Scal {
    uint prefix, remaining;
    float c1[4];
    float c2;
};

__device__ __forceinline__ uint f2ord(float f) {
    uint b = __float_as_uint(f);
    return (b & 0x80000000u) ? ~b : (b | 0x80000000u);
}
__device__ __forceinline__ float lrelu(float v) { return v > 0.f ? v : 0.2f * v; }
__device__ __forceinline__ float2 bf2f2(uint u) {
    return make_float2(__uint_as_float(u << 16), __uint_as_float(u & 0xFFFF0000u));
}
__device__ __forceinline__ uint f2bf2(float a, float b) {
    __hip_bfloat162 h;
    h.x = __float2bfloat16(a);
    h.y = __float2bfloat16(b);
    return *(uint*)&h;
}

// ---------------- init (+ folded constK) ----------------
__global__ __launch_bounds__(256) void initK(uint* bcnt, uint* hist, Scal* sc,
                                             const float* We1, const float* ae1,
                                             const float* We2, const float* ae2) {
    int i = blockIdx.x * 256 + threadIdx.x;
    if (i < NBK) bcnt[i] = 0u;
    if (i < 256) hist[i] = 0u;
    if (i == 0) {
        sc->prefix = 0u; sc->remaining = Kk;
        for (int h = 0; h < 4; h++) {
            float s = 0.f;
            for (int d = 0; d < 4; d++) s += We1[h * 4 + d] * ae1[h * 4 + d];
            sc->c1[h] = s;
        }
        float s2 = 0.f;
        for (int d = 0; d < 128; d++) s2 += We2[d] * ae2[d];
        sc->c2 = s2;
    }
}

// ---------------- layer 1: node GEMM + attn coefficients (bf16 hpre) ----------------
__global__ __launch_bounds__(256) void nodeL1(const float* __restrict__ x,
                                              const float* __restrict__ W1,
                                              const float* __restrict__ as1,
                                              const float* __restrict__ ad1,
                                              uint* __restrict__ hpreB,
                                              float* __restrict__ alS1,
                                              float* __restrict__ alD1) {
    __shared__ float Ws[128 * 16];
    __shared__ float s_as[16], s_ad[16];
    for (int i = threadIdx.x; i < 2048; i += 256) Ws[i] = W1[i];
    if (threadIdx.x < 16) { s_as[threadIdx.x] = as1[threadIdx.x]; s_ad[threadIdx.x] = ad1[threadIdx.x]; }
    __syncthreads();
    int n = blockIdx.x * 256 + threadIdx.x;
    if (n >= Nn) return;
    float acc[16];
#pragma unroll
    for (int j = 0; j < 16; j++) acc[j] = 0.f;
    const float4* xr = (const float4*)(x + (size_t)n * 128);
    for (int t4 = 0; t4 < 32; t4++) {
        float4 xv = xr[t4];
#pragma unroll
        for (int j = 0; j < 16; j++) {
            acc[j] += xv.x * Ws[(t4 * 4 + 0) * 16 + j];
            acc[j] += xv.y * Ws[(t4 * 4 + 1) * 16 + j];
            acc[j] += xv.z * Ws[(t4 * 4 + 2) * 16 + j];
            acc[j] += xv.w * Ws[(t4 * 4 + 3) * 16 + j];
        }
    }
    uint h8[8];
#pragma unroll
    for (int j = 0; j < 8; j++) h8[j] = f2bf2(acc[2 * j], acc[2 * j + 1]);
    uint4* hp = (uint4*)(hpreB + (size_t)n * 8);
    hp[0] = make_uint4(h8[0], h8[1], h8[2], h8[3]);
    hp[1] = make_uint4(h8[4], h8[5], h8[6], h8[7]);
#pragma unroll
    for (int h = 0; h < 4; h++) {
        float s = 0.f, d = 0.f;
#pragma unroll
        for (int q = 0; q < 4; q++) {
            s += acc[h * 4 + q] * s_as[h * 4 + q];
            d += acc[h * 4 + q] * s_ad[h * 4 + q];
        }
        alS1[n * 4 + h] = s;
        alD1[n * 4 + h] = d;
    }
}

// ---------------- CSR build: bucket sort (r16 geometry) ----------------
__global__ __launch_bounds__(256) void bucketCnt(const int* __restrict__ ei, uint* __restrict__ bcnt) {
    __shared__ uint h[NBK];
    if (threadIdx.x < NBK) h[threadIdx.x] = 0u;
    __syncthreads();
    for (int e = blockIdx.x * 256 + threadIdx.x; e < Ee; e += gridDim.x * 256)
        atomicAdd(&h[((uint)ei[Ee + e]) >> 9], 1u);
    __syncthreads();
    if (threadIdx.x < NBK && h[threadIdx.x]) atomicAdd(&bcnt[threadIdx.x], h[threadIdx.x]);
}

__global__ __launch_bounds__(256) void scanBk(const uint* __restrict__ bcnt, uint* __restrict__ boff,
                                              uint* __restrict__ gcur) {
    __shared__ uint s[256];
    int t = threadIdx.x;
    uint v = (t < NBK) ? bcnt[t] : 0u;
    s[t] = v;
    __syncthreads();
    for (int off = 1; off < 256; off <<= 1) {
        uint u = (t >= off) ? s[t - off] : 0u;
        __syncthreads();
        s[t] += u;
        __syncthreads();
    }
    if (t < NBK) { boff[t] = s[t] - v; gcur[t] = 0u; }
    if (t == 0) boff[NBK] = Ee;
}

__global__ __launch_bounds__(256) void binScat(const int* __restrict__ ei, const float* __restrict__ ea,
                                               const uint* __restrict__ boff, uint* __restrict__ gcur,
                                               uint2* __restrict__ bsE, ushort* __restrict__ bsD) {
    __shared__ uint h[NBK], base[NBK], h2[NBK];
    int t = threadIdx.x;
    if (t < NBK) h[t] = 0u;
    __syncthreads();
    int estart = blockIdx.x * CHK;
    int eend = min(Ee, estart + CHK);
    for (int e = estart + t; e < eend; e += 256)
        atomicAdd(&h[((uint)ei[Ee + e]) >> 9], 1u);
    __syncthreads();
    if (t < NBK) { base[t] = atomicAdd(&gcur[t], h[t]); h2[t] = 0u; }
    __syncthreads();
    for (int e = estart + t; e < eend; e += 256) {
        uint d = (uint)ei[Ee + e];
        uint b = d >> 9;
        uint r = atomicAdd(&h2[b], 1u);
        uint pos = boff[b] + base[b] + r;
        bsE[pos] = make_uint2((uint)ei[e], __float_as_uint(ea[e]));
        bsD[pos] = (ushort)(d & 511u);
    }
}

// rank + scan + place fused: 1 block per 512-dst bucket. Writes rowstart AND csr_p8.
__global__ __launch_bounds__(256) void rankPlace(const uint* __restrict__ boff, const uint2* __restrict__ bsE,
                                                 const ushort* __restrict__ bsD,
                                                 uint2* __restrict__ csr_p8, uint* __restrict__ rowstart) {
    __shared__ uint ldeg[512];
    __shared__ uint lscan[512];
    __shared__ uint ps[256];
    int b = blockIdx.x, t = threadIdx.x;
    ldeg[t] = 0u; ldeg[t + 256] = 0u;
    __syncthreads();
    uint r0 = boff[b], r1 = boff[b + 1];
    for (uint i = r0 + t; i < r1; i += 256)
        atomicAdd(&ldeg[bsD[i]], 1u);
    __syncthreads();
    uint pv = ldeg[2 * t] + ldeg[2 * t + 1];
    ps[t] = pv;
    __syncthreads();
    for (int off = 1; off < 256; off <<= 1) {
        uint u = (t >= off) ? ps[t - off] : 0u;
        __syncthreads();
        ps[t] += u;
        __syncthreads();
    }
    uint pbase = ps[t] - pv;
    lscan[2 * t] = pbase;
    lscan[2 * t + 1] = pbase + ldeg[2 * t];
    __syncthreads();
    uint bb = boff[b];
    int nd = b * 512 + t;
    if (nd < Nn) rowstart[nd] = bb + lscan[t];
    nd = b * 512 + 256 + t;
    if (nd < Nn) rowstart[nd] = bb + lscan[256 + t];
    if (b == 0 && t == 0) rowstart[Nn] = Ee;
    ldeg[t] = 0u; ldeg[t + 256] = 0u;
    __syncthreads();
    for (uint i = r0 + t; i < r1; i += 256) {
        ushort dl = bsD[i];
        uint r = atomicAdd(&ldeg[dl], 1u);
        csr_p8[bb + lscan[dl] + r] = bsE[i];
    }
}

// ---------------- layer-1 gather: fused partial, thread per (dst,head), bf16 hpre ----------------
__global__ __launch_bounds__(256) void gather1f(const uint2* __restrict__ csr_p8,
                                                const uint* __restrict__ rowstart,
                                                const float* __restrict__ alS1, const float* __restrict__ alD1,
                                                const uint* __restrict__ hpreB, const Scal* __restrict__ scc,
                                                const float* __restrict__ b1, const float* __restrict__ Wrel,
                                                const float* __restrict__ Wroot,
                                                float* __restrict__ h1, float* __restrict__ p,
                                                float* __restrict__ q) {
    int tid = blockIdx.x * 256 + threadIdx.x;
    if (tid >= Nn * 4) return;
    int d = tid >> 2, h = tid & 3;
    uint r0 = rowstart[d], r1 = rowstart[d + 1];
    float ad = alD1[tid];
    float c1h = scc->c1[h];
    float den = 0.f;
    float4 acc = {0.f, 0.f, 0.f, 0.f};
#pragma unroll 8
    for (uint i = r0; i < r1; i++) {
        uint2 p8 = csr_p8[i];
        int s = (int)p8.x;
        float e = __expf(lrelu(alS1[s * 4 + h] + __uint_as_float(p8.y) * c1h + ad));
        uint2 hb = *(const uint2*)(hpreB + (size_t)s * 8 + h * 2);
        float2 f0 = bf2f2(hb.x), f1 = bf2f2(hb.y);
        den += e;
        acc.x += e * f0.x; acc.y += e * f0.y;
        acc.z += e * f1.x; acc.w += e * f1.y;
    }
    float inv = 1.f / fmaxf(den, 1e-16f);
    float4 o;
    o.x = fmaxf(acc.x * inv + b1[h * 4 + 0], 0.f);
    o.y = fmaxf(acc.y * inv + b1[h * 4 + 1], 0.f);
    o.z = fmaxf(acc.z * inv + b1[h * 4 + 2], 0.f);
    o.w = fmaxf(acc.w * inv + b1[h * 4 + 3], 0.f);
    *(float4*)(h1 + (size_t)d * 16 + h * 4) = o;
    float pp = o.x * Wrel[h * 4 + 0] + o.y * Wrel[h * 4 + 1] + o.z * Wrel[h * 4 + 2] + o.w * Wrel[h * 4 + 3];
    float qq = o.x * Wroot[h * 4 + 0] + o.y * Wroot[h * 4 + 1] + o.z * Wroot[h * 4 + 2] + o.w * Wroot[h * 4 + 3];
    pp += __shfl_xor(pp, 1); pp += __shfl_xor(pp, 2);
    qq += __shfl_xor(qq, 1); qq += __shfl_xor(qq, 2);
    if (h == 0) { p[d] = pp; q[d] = qq; }
}

// ---------------- SAGPool score + first radix histogram (shift=24) fused ----------------
__global__ __launch_bounds__(256) void scoreH(const uint2* __restrict__ csr_p8, const uint* __restrict__ rowstart,
                                              const float* __restrict__ p, const float* __restrict__ q,
                                              const float* __restrict__ brel,
                                              float* __restrict__ score, uint* __restrict__ dkey,
                                              uint* __restrict__ hist) {
    __shared__ uint lh[256];
    lh[threadIdx.x] = 0u;
    __syncthreads();
    int d = blockIdx.x * 256 + threadIdx.x;
    if (d < Nn) {
        uint r0 = rowstart[d], r1 = rowstart[d + 1];
        float s = brel[0] + q[d];
#pragma unroll 8
        for (uint i = r0; i < r1; i++) s += p[(int)csr_p8[i].x];
        score[d] = s;
        uint k = ~f2ord(s);
        dkey[d] = k;
        atomicAdd(&lh[k >> 24], 1u);
    }
    __syncthreads();
    if (lh[threadIdx.x]) atomicAdd(&hist[threadIdx.x], lh[threadIdx.x]);
}

// ---------------- radix select (multi-block) ----------------
__global__ __launch_bounds__(256) void histK(const uint* __restrict__ dkey, const Scal* __restrict__ sc,
                                             uint* __restrict__ hist, int shift) {
    __shared__ uint lh[256];
    lh[threadIdx.x] = 0u;
    __syncthreads();
    int i = blockIdx.x * 256 + threadIdx.x;
    if (i < Nn) {
        uint d = dkey[i];
        if ((d >> (shift + 8)) == sc->prefix) atomicAdd(&lh[(d >> shift) & 255u], 1u);
    }
    __syncthreads();
    if (lh[threadIdx.x]) atomicAdd(&hist[threadIdx.x], lh[threadIdx.x]);
}

__global__ __launch_bounds__(256) void selP(Scal* sc, uint* hist) {
    __shared__ uint s[256];
    int t = threadIdx.x;
    uint c = hist[t];
    s[t] = c;
    __syncthreads();
    for (int off = 1; off < 256; off <<= 1) {
        uint v = (t >= off) ? s[t - off] : 0u;
        __syncthreads();
        s[t] += v;
        __syncthreads();
    }
    uint rem = sc->remaining;
    uint cum = s[t];
    uint cumex = cum - c;
    if (cum >= rem && cumex < rem) {
        sc->remaining = rem - cumex;
        sc->prefix = (sc->prefix << 8) | (uint)t;
    }
    hist[t] = 0u;
}

// eq-count per block (needEq == sc->remaining after last selP)
__global__ __launch_bounds__(256) void eqCnt(const uint* __restrict__ dkey, const Scal* __restrict__ sc,
                                             uint* __restrict__ blkEq) {
    int i = blockIdx.x * 256 + threadIdx.x;
    uint ut = sc->prefix;
    bool eq = (i < Nn) && (dkey[i] == ut);
    __shared__ uint se[4];
    unsigned long long be = __ballot(eq);
    int lane = threadIdx.x & 63, w = threadIdx.x >> 6;
    if (lane == 0) se[w] = (uint)__popcll(be);
    __syncthreads();
    if (threadIdx.x == 0) blkEq[blockIdx.x] = se[0] + se[1] + se[2] + se[3];
}

__global__ __launch_bounds__(512) void prefE(const uint* __restrict__ blkEq, uint* __restrict__ eqPref) {
    __shared__ uint se[512];
    int t = threadIdx.x;
    uint e = (t < NB) ? blkEq[t] : 0u;
    se[t] = e;
    __syncthreads();
    for (int off = 1; off < 512; off <<= 1) {
        uint v1 = (t >= off) ? se[t - off] : 0u;
        __syncthreads();
        se[t] += v1;
        __syncthreads();
    }
    if (t < NB) eqPref[t] = se[t] - e;
}

__global__ __launch_bounds__(256) void keptK(const uint* __restrict__ dkey, const Scal* __restrict__ sc,
                                             const uint* __restrict__ eqPref, int* __restrict__ kept) {
    int i = blockIdx.x * 256 + threadIdx.x;
    uint ut = sc->prefix, needEq = sc->remaining;
    bool inr = i < Nn;
    uint d = inr ? dkey[i] : 0xFFFFFFFFu;
    bool isLt = inr && (d < ut);
    bool isEq = inr && (d == ut);
    __shared__ uint wcnt[4];
    unsigned long long mask = __ballot(isEq);
    int lane = threadIdx.x & 63, w = threadIdx.x >> 6;
    uint lanePre = (uint)__popcll(mask & ((1ull << lane) - 1ull));
    if (lane == 0) wcnt[w] = (uint)__popcll(mask);
    __syncthreads();
    uint wo = 0;
    for (int qq = 0; qq < 4; qq++) if (qq < w) wo += wcnt[qq];
    uint rank = eqPref[blockIdx.x] + wo + lanePre;
    if (inr) kept[i] = (isLt || (isEq && rank < needEq)) ? 1 : 0;
}

// ---------------- layer 2 node transform: bf16 rows; alS2k = kept ? alS2 : -1e30 ----------------
__global__ __launch_bounds__(256) void nodeL2(const float* __restrict__ h1, const float* __restrict__ score,
                                              const int* __restrict__ kept, const float* __restrict__ W2,
                                              const float* __restrict__ as2, const float* __restrict__ ad2,
                                              __hip_bfloat162* __restrict__ h2b, float* __restrict__ alS2k,
                                              float* __restrict__ alD2) {
    __shared__ float Ws[16 * 128];
    for (int i = threadIdx.x; i < 2048; i += 256) Ws[i] = W2[i];
    __syncthreads();
    int wid = (blockIdx.x * 256 + threadIdx.x) >> 6;
    int lane = threadIdx.x & 63;
    if (wid >= Nn) return;
    int n = wid;
    if (!kept[n]) { if (lane == 0) alS2k[n] = -1e30f; return; }
    float t = tanhf(score[n]);
    float x2[16];
    const float* hr = h1 + (size_t)n * 16;
#pragma unroll
    for (int j = 0; j < 16; j++) x2[j] = hr[j] * t;
    int d0 = 2 * lane, d1 = 2 * lane + 1;
    float a0 = 0.f, a1 = 0.f;
    const float2* Wv = (const float2*)Ws;
#pragma unroll
    for (int j = 0; j < 16; j++) {
        float2 wv = Wv[j * 64 + lane];
        a0 += x2[j] * wv.x;
        a1 += x2[j] * wv.y;
    }
    __hip_bfloat162 hb;
    hb.x = __float2bfloat16(a0);
    hb.y = __float2bfloat16(a1);
    h2b[(size_t)n * 64 + lane] = hb;
    float s = a0 * as2[d0] + a1 * as2[d1];
    float dd = a0 * ad2[d0] + a1 * ad2[d1];
#pragma unroll
    for (int off = 32; off; off >>= 1) { s += __shfl_xor(s, off); dd += __shfl_xor(dd, off); }
    if (lane == 0) { alS2k[n] = s; alD2[n] = dd; }
}

// ---------------- layer-2 gather + fused pooling partials ----------------
__global__ __launch_bounds__(256) void gather2g(const uint2* __restrict__ csr_p8,
                                                const uint* __restrict__ rowstart,
                                                const float* __restrict__ alS2k, const float* __restrict__ alD2,
                                                const Scal* __restrict__ scc,
                                                const __hip_bfloat162* __restrict__ h2b, const float* __restrict__ b2,
                                                const float* __restrict__ Wg, const float* __restrict__ bg,
                                                float* __restrict__ pacc, float* __restrict__ pmx,
                                                float* __restrict__ pden) {
    __shared__ float sAtt[4][16][8];
    __shared__ float sMx[4][16][8];
    __shared__ float sDen[4];
    int w = threadIdx.x >> 6, lane = threadIdx.x & 63;
    int g = lane >> 4, t = lane & 15;
    float4 b2a = ((const float4*)b2)[t * 2], b2b = ((const float4*)b2)[t * 2 + 1];
    float4 wga = ((const float4*)Wg)[t * 2], wgb = ((const float4*)Wg)[t * 2 + 1];
    float bg0 = bg[0];
    float c2 = scc->c2;
    const uint* h2u = (const uint*)h2b;
    float att[8], mx8[8], denP = 0.f;
#pragma unroll
    for (int j = 0; j < 8; j++) { att[j] = 0.f; mx8[j] = 0.f; }
    for (int n = blockIdx.x * 4 + w; n < Nn; n += G2B * 4) {
        float sk = alS2k[n];
        if (sk <= -1e29f) continue;   // not kept (sentinel)
        float ad = alD2[n];
        uint r0 = rowstart[n];
        uint len = rowstart[n + 1] - r0;
        float den = 0.f;
        float acc[8];
#pragma unroll
        for (int d = 0; d < 8; d++) acc[d] = 0.f;
#pragma unroll 4
        for (uint base = 0; base < len; base += 4) {
            uint off = base + (uint)g;
            bool act = off < len;
            uint sidx = act ? (r0 + off) : (r0 + len - 1);
            uint2 p8 = csr_p8[sidx];
            int s = (int)p8.x;
            float pv = alS2k[s] + __uint_as_float(p8.y) * c2;
            pv = act ? pv : -1e30f;
            float c = __expf(lrelu(pv + ad));
            uint4 hv = *(const uint4*)(h2u + (size_t)s * 64 + t * 4);
            den += c;
            float2 f;
            f = bf2f2(hv.x); acc[0] += c * f.x; acc[1] += c * f.y;
            f = bf2f2(hv.y); acc[2] += c * f.x; acc[3] += c * f.y;
            f = bf2f2(hv.z); acc[4] += c * f.x; acc[5] += c * f.y;
            f = bf2f2(hv.w); acc[6] += c * f.x; acc[7] += c * f.y;
        }
#pragma unroll
        for (int d = 0; d < 8; d++) {
            acc[d] += __shfl_xor(acc[d], 16);
            acc[d] += __shfl_xor(acc[d], 32);
        }
        den += __shfl_xor(den, 16);
        den += __shfl_xor(den, 32);
        float inv = 1.f / fmaxf(den, 1e-16f);
        float o[8];
        o[0] = fmaxf(acc[0] * inv + b2a.x, 0.f);
        o[1] = fmaxf(acc[1] * inv + b2a.y, 0.f);
        o[2] = fmaxf(acc[2] * inv + b2a.z, 0.f);
        o[3] = fmaxf(acc[3] * inv + b2a.w, 0.f);
        o[4] = fmaxf(acc[4] * inv + b2b.x, 0.f);
        o[5] = fmaxf(acc[5] * inv + b2b.y, 0.f);
        o[6] = fmaxf(acc[6] * inv + b2b.z, 0.f);
        o[7] = fmaxf(acc[7] * inv + b2b.w, 0.f);
        float gp = o[0] * wga.x + o[1] * wga.y + o[2] * wga.z + o[3] * wga.w +
                   o[4] * wgb.x + o[5] * wgb.y + o[6] * wgb.z + o[7] * wgb.w;
#pragma unroll
        for (int off = 8; off; off >>= 1) gp += __shfl_xor(gp, off);
        float e = __expf(gp + bg0);
        denP += e;
#pragma unroll
        for (int j = 0; j < 8; j++) {
            att[j] += e * o[j];
            mx8[j] = fmaxf(mx8[j], o[j]);
        }
    }
    if (g == 0) {
#pragma unroll
        for (int j = 0; j < 8; j++) { sAtt[w][t][j] = att[j]; sMx[w][t][j] = mx8[j]; }
    }
    if (lane == 0) sDen[w] = denP;
    __syncthreads();
    int tid = threadIdx.x;
    if (tid < 128) {
        int tt = tid >> 3, j = tid & 7;
        float a = sAtt[0][tt][j] + sAtt[1][tt][j] + sAtt[2][tt][j] + sAtt[3][tt][j];
        float m = fmaxf(fmaxf(sMx[0][tt][j], sMx[1][tt][j]), fmaxf(sMx[2][tt][j], sMx[3][tt][j]));
        pacc[(size_t)blockIdx.x * 128 + tid] = a;
        pmx[(size_t)blockIdx.x * 128 + tid] = m;
    }
    if (tid == 0) pden[blockIdx.x] = sDen[0] + sDen[1] + sDen[2] + sDen[3];
}

// ---------------- final reduction + output (fused): 128 blocks, one per dim ----------------
__global__ __launch_bounds__(256) void gateOut(const float* __restrict__ pacc, const float* __restrict__ pmx,
                                               const float* __restrict__ pden, float* __restrict__ out) {
    __shared__ float r[256];
    __shared__ float rd[256];
    int b = blockIdx.x, tid = threadIdx.x;
    float a = 0.f, m = 0.f, dsum = 0.f;
    for (int i = tid; i < G2B; i += 256) {
        a += pacc[(size_t)i * 128 + b];
        m = fmaxf(m, pmx[(size_t)i * 128 + b]);
        dsum += pden[i];
    }
    r[tid] = a; rd[tid] = dsum;
    __syncthreads();
    for (int off = 128; off; off >>= 1) {
        if (tid < off) { r[tid] += r[tid + off]; rd[tid] += rd[tid + off]; }
        __syncthreads();
    }
    float asum = r[0], deng = rd[0];
    __syncthreads();
    r[tid] = m;
    __syncthreads();
    for (int off = 128; off; off >>= 1) {
        if (tid < off) r[tid] = fmaxf(r[tid], r[tid + off]);
        __syncthreads();
    }
    if (tid == 0) {
        out[b] = asum / deng;
        out[128 + b] = r[0];
    }
}

extern "C" void kernel_launch(void* const* d_in, const int* in_sizes, int n_in,
                              void* d_out, int out_size, void* d_ws, size_t ws_size,
                              hipStream_t stream) {
    const float* x = (const float*)d_in[0];
    const int* ei = (const int*)d_in[1];
    const float* ea = (const float*)d_in[2];
    const float* W1 = (const float*)d_in[3];
    const float* as1 = (const float*)d_in[4];
    const float* ad1 = (const float*)d_in[5];
    const float* We1 = (const float*)d_in[6];
    const float* ae1 = (const float*)d_in[7];
    const float* b1 = (const float*)d_in[8];
    const float* Wrel = (const float*)d_in[9];
    const float* brel = (const float*)d_in[10];
    const float* Wroot = (const float*)d_in[11];
    const float* W2 = (const float*)d_in[12];
    const float* as2 = (const float*)d_in[13];
    const float* ad2 = (const float*)d_in[14];
    const float* We2 = (const float*)d_in[15];
    const float* ae2 = (const float*)d_in[16];
    const float* b2 = (const float*)d_in[17];
    const float* Wg = (const float*)d_in[18];
    const float* bg = (const float*)d_in[19];
    float* out = (float*)d_out;

    float* base = (float*)d_ws;
    size_t o = 0;
    auto alloc = [&](size_t nf) { float* p2 = base + o; o += nf; return p2; };
    uint2* bsE = (uint2*)alloc((size_t)Ee * 2);
    ushort* bsD = (ushort*)alloc((size_t)Ee / 2);
    uint2* csr_p8 = (uint2*)alloc((size_t)Ee * 2);
    __hip_bfloat162* h2b = (__hip_bfloat162*)alloc((size_t)Nn * 64);
    uint* hpreB = (uint*)alloc((size_t)Nn * 8);   // bf16 [N][16]
    float* h1 = alloc((size_t)Nn * 16);
    float* pacc = alloc((size_t)G2B * 128);
    float* pmx = alloc((size_t)G2B * 128);
    float* pden = alloc(G2B);
    float* alS1 = alloc((size_t)Nn * 4);
    float* alD1 = alloc((size_t)Nn * 4);
    float* p = alloc(Nn);
    float* q = alloc(Nn);
    float* score = alloc(Nn);
    uint* dkey = (uint*)alloc(Nn);
    int* kept = (int*)alloc(Nn);
    float* alS2k = alloc(Nn);
    float* alD2 = alloc(Nn);
    uint* rowstart = (uint*)alloc(Nn + 1);
    uint* hist = (uint*)alloc(256);
    uint* blkEq = (uint*)alloc(NB);
    uint* eqPref = (uint*)alloc(NB);
    uint* bcnt = (uint*)alloc(NBK);
    uint* boff = (uint*)alloc(NBK + 1);
    uint* gcur = (uint*)alloc(NBK);
    Scal* sc = (Scal*)alloc(64);

    auto cdiv = [](long a, long b) { return (int)((a + b - 1) / b); };

    initK<<<NB, 256, 0, stream>>>(bcnt, hist, sc, We1, ae1, We2, ae2);
    nodeL1<<<NB, 256, 0, stream>>>(x, W1, as1, ad1, hpreB, alS1, alD1);
    bucketCnt<<<512, 256, 0, stream>>>(ei, bcnt);
    scanBk<<<1, 256, 0, stream>>>(bcnt, boff, gcur);
    binScat<<<cdiv(Ee, CHK), 256, 0, stream>>>(ei, ea, boff, gcur, bsE, bsD);
    rankPlace<<<NBK, 256, 0, stream>>>(boff, bsE, bsD, csr_p8, rowstart);
    gather1f<<<cdiv((long)Nn * 4, 256), 256, 0, stream>>>(csr_p8, rowstart, alS1, alD1, hpreB, sc,
                                                          b1, Wrel, Wroot, h1, p, q);
    scoreH<<<NB, 256, 0, stream>>>(csr_p8, rowstart, p, q, brel, score, dkey, hist);
    selP<<<1, 256, 0, stream>>>(sc, hist);
    for (int shift = 16; shift >= 0; shift -= 8) {
        histK<<<NB, 256, 0, stream>>>(dkey, sc, hist, shift);
        selP<<<1, 256, 0, stream>>>(sc, hist);
    }
    eqCnt<<<NB, 256, 0, stream>>>(dkey, sc, blkEq);
    prefE<<<1, 512, 0, stream>>>(blkEq, eqPref);
    keptK<<<NB, 256, 0, stream>>>(dkey, sc, eqPref, kept);
    nodeL2<<<cdiv(Nn, 4), 256, 0, stream>>>(h1, score, kept, W2, as2, ad2, h2b, alS2k, alD2);
    gather2g<<<G2B, 256, 0, stream>>>(csr_p8, rowstart, alS2k, alD2, sc,
                                      h2b, b2, Wg, bg, pacc, pmx, pden);
    gateOut<<<128, 256, 0, stream>>>(pacc, pmx, pden, out);
}